// Round 2
// 95.901 us; speedup vs baseline: 1.0414x; 1.0414x over previous
//
#include <hip/hip_runtime.h>
#include <math.h>

#define BATCH 128
#define FEAT  1024
#define CLS   500
#define HID   512
#define ISPL  8          // img split-K count   (Ks = 128 = 8 BK-steps)
#define ASPL  6          // attr split-K count  (BK-steps 11/11/11/11/10/10)

constexpr int BM = 64, BN = 64, BK = 16;
constexpr int TB = 16, TC = 16, HC = 256;

constexpr int NIMG  = BATCH * HID;   // 65536
constexpr int NATTR = CLS * HID;     // 256000

// ---------------------------------------------------------------------------
// Balanced split-K GEMM: exactly 512 blocks = 2 blocks/CU on 256 CUs.
//   bid <  128 : img path  — z = bid>>4 (8 splits), 2 m-tiles x 8 n-tiles
//   bid >= 128 : attr path — z = a/64   (6 splits), 8 m-tiles x 8 n-tiles
// C = A * B^T, A (M,K) row-major, B rows of length ldb=2*FEAT.
// ---------------------------------------------------------------------------
__global__ __launch_bounds__(256) void gemm_bt_splitk(
    const float* __restrict__ img, const float* __restrict__ attr,
    const float* __restrict__ W1,
    float* __restrict__ imgP, float* __restrict__ attrP)
{
    __shared__ float As[BK][BM + 4];
    __shared__ float Bs[BK][BN + 4];

    const int t   = threadIdx.x;
    const int bid = blockIdx.x;

    const float* A;
    float* P;
    int M, boff, m0, n0, kt0, nkt;
    if (bid < 128) {                       // image path
        const int z   = bid >> 4;          // 0..7
        const int rem = bid & 15;
        A = img; P = imgP + (size_t)z * NIMG;
        M = BATCH; boff = 0;
        m0 = (rem >> 3) * BM;              // 0..1
        n0 = (rem & 7) * BN;
        kt0 = z * 8;  nkt = 8;             // 8 BK-steps per split
    } else {                               // attribute path
        const int a   = bid - 128;
        const int z   = a / 64;            // 0..5
        const int rem = a & 63;
        A = attr; P = attrP + (size_t)z * NATTR;
        M = CLS; boff = FEAT;
        m0 = (rem >> 3) * BM;              // 0..7
        n0 = (rem & 7) * BN;
        kt0 = (z < 4) ? z * 11 : 44 + (z - 4) * 10;
        nkt = (z < 4) ? 11 : 10;           // 11+11+11+11+10+10 = 64 steps
    }

    const int K   = FEAT;
    const int ldb = 2 * FEAT;

    const int lrow = t >> 2;               // 0..63
    const int lk   = (t & 3) * 4;          // 0,4,8,12

    const int tn = t & 15;                 // n micro index
    const int tm = t >> 4;                 // m micro index

    float acc[4][4];
    #pragma unroll
    for (int i = 0; i < 4; ++i)
        #pragma unroll
        for (int j = 0; j < 4; ++j) acc[i][j] = 0.f;

    for (int kt = 0; kt < nkt; ++kt) {
        const int kk = (kt0 + kt) * BK;
        {
            const int m = m0 + lrow;
            float4 av = make_float4(0.f, 0.f, 0.f, 0.f);
            if (m < M)
                av = *(const float4*)&A[(size_t)m * K + kk + lk];
            As[lk + 0][lrow] = av.x;
            As[lk + 1][lrow] = av.y;
            As[lk + 2][lrow] = av.z;
            As[lk + 3][lrow] = av.w;

            const int n = n0 + lrow;       // N = 512, always in range
            const float4 bv =
                *(const float4*)&W1[(size_t)n * ldb + boff + kk + lk];
            Bs[lk + 0][lrow] = bv.x;
            Bs[lk + 1][lrow] = bv.y;
            Bs[lk + 2][lrow] = bv.z;
            Bs[lk + 3][lrow] = bv.w;
        }
        __syncthreads();
        #pragma unroll
        for (int k = 0; k < BK; ++k) {
            const float4 a = *(const float4*)&As[k][tm * 4];
            const float4 b = *(const float4*)&Bs[k][tn * 4];
            acc[0][0] = fmaf(a.x, b.x, acc[0][0]);
            acc[0][1] = fmaf(a.x, b.y, acc[0][1]);
            acc[0][2] = fmaf(a.x, b.z, acc[0][2]);
            acc[0][3] = fmaf(a.x, b.w, acc[0][3]);
            acc[1][0] = fmaf(a.y, b.x, acc[1][0]);
            acc[1][1] = fmaf(a.y, b.y, acc[1][1]);
            acc[1][2] = fmaf(a.y, b.z, acc[1][2]);
            acc[1][3] = fmaf(a.y, b.w, acc[1][3]);
            acc[2][0] = fmaf(a.z, b.x, acc[2][0]);
            acc[2][1] = fmaf(a.z, b.y, acc[2][1]);
            acc[2][2] = fmaf(a.z, b.z, acc[2][2]);
            acc[2][3] = fmaf(a.z, b.w, acc[2][3]);
            acc[3][0] = fmaf(a.w, b.x, acc[3][0]);
            acc[3][1] = fmaf(a.w, b.y, acc[3][1]);
            acc[3][2] = fmaf(a.w, b.z, acc[3][2]);
            acc[3][3] = fmaf(a.w, b.w, acc[3][3]);
        }
        __syncthreads();
    }

    #pragma unroll
    for (int i = 0; i < 4; ++i) {
        const int m = m0 + tm * 4 + i;
        if (m < M) {
            float4 v = make_float4(acc[i][0], acc[i][1], acc[i][2], acc[i][3]);
            *(float4*)&P[(size_t)m * HID + n0 + tn * 4] = v;
        }
    }
}

// ---------------------------------------------------------------------------
// Merge split-K partials (8 img layers, 6 attr layers); fold b1 into img.
// One float4 per thread.
// ---------------------------------------------------------------------------
__global__ __launch_bounds__(256) void merge_kernel(
    const float* __restrict__ imgP, const float* __restrict__ attrP,
    const float* __restrict__ b1,
    float* __restrict__ imgF, float* __restrict__ attrF)
{
    const int g = blockIdx.x * 256 + threadIdx.x;     // float4 index
    const float4* imgP4  = (const float4*)imgP;
    const float4* attrP4 = (const float4*)attrP;
    const float4* b14    = (const float4*)b1;
    if (g < NIMG / 4) {
        float4 s = imgP4[g];
        #pragma unroll
        for (int zz = 1; zz < ISPL; ++zz) {
            const float4 p = imgP4[zz * (NIMG / 4) + g];
            s.x += p.x; s.y += p.y; s.z += p.z; s.w += p.w;
        }
        const float4 bb = b14[g & (HID / 4 - 1)];
        s.x += bb.x; s.y += bb.y; s.z += bb.z; s.w += bb.w;
        ((float4*)imgF)[g] = s;
    } else if (g < NIMG / 4 + NATTR / 4) {
        const int j = g - NIMG / 4;
        float4 s = attrP4[j];
        #pragma unroll
        for (int zz = 1; zz < ASPL; ++zz) {
            const float4 p = attrP4[zz * (NATTR / 4) + j];
            s.x += p.x; s.y += p.y; s.z += p.z; s.w += p.w;
        }
        ((float4*)attrF)[j] = s;
    }
}

// ---------------------------------------------------------------------------
// Pair kernel: out[b,c] = sigmoid( sum_h relu(imgF[b,h]+attrF[c,h]) * W2[h] + b2 )
// 16x16 (b,c) tile per block, one pair per thread, h staged in LDS chunks.
// ---------------------------------------------------------------------------
__global__ __launch_bounds__(256) void pair_kernel(
    const float* __restrict__ imgF, const float* __restrict__ attrF,
    const float* __restrict__ W2, const float* __restrict__ b2,
    float* __restrict__ out)
{
    __shared__ float U[TB][HC + 4];
    __shared__ float V[TC][HC + 4];
    __shared__ float w2s[HID];

    const int t  = threadIdx.x;
    const int c0 = blockIdx.x * TC;
    const int b0 = blockIdx.y * TB;

    w2s[t]       = W2[t];
    w2s[t + 256] = W2[t + 256];

    const int ci = t & 15;
    const int bi = t >> 4;

    float acc = 0.f;
    for (int hc = 0; hc < HID; hc += HC) {
        __syncthreads();   // covers w2s on first iter, U/V reuse after
        #pragma unroll
        for (int rep = 0; rep < 4; ++rep) {
            const int e   = rep * 256 + t;        // 0..1023
            const int row = e >> 6;               // 0..15
            const int c4  = (e & 63) * 4;         // 0..252
            *(float4*)&U[row][c4] =
                *(const float4*)&imgF[(b0 + row) * HID + hc + c4];
            const int c = c0 + row;
            float4 v = make_float4(0.f, 0.f, 0.f, 0.f);
            if (c < CLS)
                v = *(const float4*)&attrF[c * HID + hc + c4];
            *(float4*)&V[row][c4] = v;
        }
        __syncthreads();
        #pragma unroll
        for (int h4 = 0; h4 < HC / 4; ++h4) {
            const float4 u = *(const float4*)&U[bi][h4 * 4];
            const float4 v = *(const float4*)&V[ci][h4 * 4];
            const float4 w = *(const float4*)&w2s[hc + h4 * 4];
            acc = fmaf(fmaxf(u.x + v.x, 0.f), w.x, acc);
            acc = fmaf(fmaxf(u.y + v.y, 0.f), w.y, acc);
            acc = fmaf(fmaxf(u.z + v.z, 0.f), w.z, acc);
            acc = fmaf(fmaxf(u.w + v.w, 0.f), w.w, acc);
        }
    }

    const int b = b0 + bi;
    const int c = c0 + ci;
    if (c < CLS) {
        const float x = acc + b2[0];
        out[b * CLS + c] = 1.f / (1.f + __expf(-x));
    }
}

// ---------------------------------------------------------------------------
extern "C" void kernel_launch(void* const* d_in, const int* in_sizes, int n_in,
                              void* d_out, int out_size, void* d_ws, size_t ws_size,
                              hipStream_t stream) {
    const float* img  = (const float*)d_in[0];   // (128, 1024)
    const float* attr = (const float*)d_in[1];   // (500, 1024)
    const float* W1   = (const float*)d_in[2];   // (512, 2048)
    const float* b1   = (const float*)d_in[3];   // (512,)
    const float* W2   = (const float*)d_in[4];   // (1, 512)
    const float* b2   = (const float*)d_in[5];   // (1,)
    float* out = (float*)d_out;                  // (128, 500)

    float* ws    = (float*)d_ws;
    float* imgP  = ws;                                   // 8*128*512
    float* attrP = imgP  + (size_t)ISPL * NIMG;          // 6*500*512
    float* imgF  = attrP + (size_t)ASPL * NATTR;         // 128*512
    float* attrF = imgF  + (size_t)NIMG;                 // 500*512

    // Stage 1: balanced split-K GEMM, 512 blocks = 2 blocks/CU exactly.
    gemm_bt_splitk<<<dim3(512), 256, 0, stream>>>(img, attr, W1, imgP, attrP);

    // Stage 2: merge partials (+b1 on img side). 80384 float4s.
    const int n4 = NIMG / 4 + NATTR / 4;                 // 80384
    merge_kernel<<<(n4 + 255) / 256, 256, 0, stream>>>(imgP, attrP, b1, imgF, attrF);

    // Stage 3: pair reduction + sigmoid
    dim3 pgrid((CLS + TC - 1) / TC, BATCH / TB);         // 32 x 8 = 256 blocks
    pair_kernel<<<pgrid, 256, 0, stream>>>(imgF, attrF, W2, b2, out);
}

// Round 3
// 94.154 us; speedup vs baseline: 1.0607x; 1.0185x over previous
//
#include <hip/hip_runtime.h>
#include <math.h>

#define BATCH 128
#define FEAT  1024
#define CLS   500
#define HID   512
#define ISPL  8          // img split-K count   (Ks = 128 = 8 BK-steps)
#define ASPL  6          // attr split-K count  (BK-steps 11/11/11/11/10/10)

constexpr int BM = 64, BN = 64, BK = 16;
constexpr int TB = 16, TC = 16;

constexpr int NIMG  = BATCH * HID;   // 65536
constexpr int NATTR = CLS * HID;     // 256000

// ---------------------------------------------------------------------------
// Balanced split-K GEMM, double-buffered LDS, one barrier per K-step.
//   bid <  128 : img path  — z = bid>>4 (8 splits), 2 m-tiles x 8 n-tiles
//   bid >= 128 : attr path — z = a/64   (6 splits), 8 m-tiles x 8 n-tiles
// C = A * B^T, A (M,K) row-major, B rows of length ldb=2*FEAT.
// 512 blocks = exactly 2 blocks/CU on 256 CUs.
// ---------------------------------------------------------------------------
__global__ __launch_bounds__(256) void gemm_bt_splitk(
    const float* __restrict__ img, const float* __restrict__ attr,
    const float* __restrict__ W1,
    float* __restrict__ imgP, float* __restrict__ attrP)
{
    __shared__ float As[2][BK][BM + 4];
    __shared__ float Bs[2][BK][BN + 4];

    const int t   = threadIdx.x;
    const int bid = blockIdx.x;

    const float* A;
    float* P;
    int M, boff, m0, n0, kt0, nkt;
    if (bid < 128) {                       // image path
        const int z   = bid >> 4;          // 0..7
        const int rem = bid & 15;
        A = img; P = imgP + (size_t)z * NIMG;
        M = BATCH; boff = 0;
        m0 = (rem >> 3) * BM;              // 0..1
        n0 = (rem & 7) * BN;
        kt0 = z * 8;  nkt = 8;             // 8 BK-steps per split
    } else {                               // attribute path
        const int a   = bid - 128;
        const int z   = a / 64;            // 0..5
        const int rem = a & 63;
        A = attr; P = attrP + (size_t)z * NATTR;
        M = CLS; boff = FEAT;
        m0 = (rem >> 3) * BM;              // 0..7
        n0 = (rem & 7) * BN;
        kt0 = (z < 4) ? z * 11 : 44 + (z - 4) * 10;
        nkt = (z < 4) ? 11 : 10;           // 11+11+11+11+10+10 = 64 steps
    }

    const int K   = FEAT;
    const int ldb = 2 * FEAT;

    const int lrow = t >> 2;               // 0..63
    const int lk   = (t & 3) * 4;          // 0,4,8,12
    const int tn   = t & 15;               // n micro index
    const int tm   = t >> 4;               // m micro index

    const int mrow = m0 + lrow;
    const bool mok = (mrow < M);
    const float* Aptr = A  + (size_t)mrow * K + lk;            // + kk
    const float* Bptr = W1 + (size_t)(n0 + lrow) * ldb + boff + lk;

    // prologue: stage K-step 0 into buffer 0
    {
        const int kk = kt0 * BK;
        float4 av = make_float4(0.f, 0.f, 0.f, 0.f);
        if (mok) av = *(const float4*)&Aptr[kk];
        const float4 bv = *(const float4*)&Bptr[kk];
        As[0][lk + 0][lrow] = av.x; As[0][lk + 1][lrow] = av.y;
        As[0][lk + 2][lrow] = av.z; As[0][lk + 3][lrow] = av.w;
        Bs[0][lk + 0][lrow] = bv.x; Bs[0][lk + 1][lrow] = bv.y;
        Bs[0][lk + 2][lrow] = bv.z; Bs[0][lk + 3][lrow] = bv.w;
    }

    float acc[4][4];
    #pragma unroll
    for (int i = 0; i < 4; ++i)
        #pragma unroll
        for (int j = 0; j < 4; ++j) acc[i][j] = 0.f;

    for (int kt = 0; kt < nkt; ++kt) {
        __syncthreads();                   // buf 'cur' ready for everyone
        const int cur  = kt & 1;
        const bool more = (kt + 1 < nkt);

        // issue next tile's global loads BEFORE compute — latency hides
        float4 av = make_float4(0.f, 0.f, 0.f, 0.f), bv;
        if (more) {
            const int kk = (kt0 + kt + 1) * BK;
            if (mok) av = *(const float4*)&Aptr[kk];
            bv = *(const float4*)&Bptr[kk];
        }

        #pragma unroll
        for (int k = 0; k < BK; ++k) {
            const float4 a = *(const float4*)&As[cur][k][tm * 4];
            const float4 b = *(const float4*)&Bs[cur][k][tn * 4];
            acc[0][0] = fmaf(a.x, b.x, acc[0][0]);
            acc[0][1] = fmaf(a.x, b.y, acc[0][1]);
            acc[0][2] = fmaf(a.x, b.z, acc[0][2]);
            acc[0][3] = fmaf(a.x, b.w, acc[0][3]);
            acc[1][0] = fmaf(a.y, b.x, acc[1][0]);
            acc[1][1] = fmaf(a.y, b.y, acc[1][1]);
            acc[1][2] = fmaf(a.y, b.z, acc[1][2]);
            acc[1][3] = fmaf(a.y, b.w, acc[1][3]);
            acc[2][0] = fmaf(a.z, b.x, acc[2][0]);
            acc[2][1] = fmaf(a.z, b.y, acc[2][1]);
            acc[2][2] = fmaf(a.z, b.z, acc[2][2]);
            acc[2][3] = fmaf(a.z, b.w, acc[2][3]);
            acc[3][0] = fmaf(a.w, b.x, acc[3][0]);
            acc[3][1] = fmaf(a.w, b.y, acc[3][1]);
            acc[3][2] = fmaf(a.w, b.z, acc[3][2]);
            acc[3][3] = fmaf(a.w, b.w, acc[3][3]);
        }

        if (more) {                        // write next tile to other buffer
            const int nxt = cur ^ 1;
            As[nxt][lk + 0][lrow] = av.x; As[nxt][lk + 1][lrow] = av.y;
            As[nxt][lk + 2][lrow] = av.z; As[nxt][lk + 3][lrow] = av.w;
            Bs[nxt][lk + 0][lrow] = bv.x; Bs[nxt][lk + 1][lrow] = bv.y;
            Bs[nxt][lk + 2][lrow] = bv.z; Bs[nxt][lk + 3][lrow] = bv.w;
        }
    }

    #pragma unroll
    for (int i = 0; i < 4; ++i) {
        const int m = m0 + tm * 4 + i;
        if (m < M) {
            float4 v = make_float4(acc[i][0], acc[i][1], acc[i][2], acc[i][3]);
            *(float4*)&P[(size_t)m * HID + n0 + tn * 4] = v;
        }
    }
}

// ---------------------------------------------------------------------------
// Merge split-K partials (8 img layers, 6 attr layers); fold b1 into img.
// One float4 per thread.
// ---------------------------------------------------------------------------
__global__ __launch_bounds__(256) void merge_kernel(
    const float* __restrict__ imgP, const float* __restrict__ attrP,
    const float* __restrict__ b1,
    float* __restrict__ imgF, float* __restrict__ attrF)
{
    const int g = blockIdx.x * 256 + threadIdx.x;     // float4 index
    const float4* imgP4  = (const float4*)imgP;
    const float4* attrP4 = (const float4*)attrP;
    const float4* b14    = (const float4*)b1;
    if (g < NIMG / 4) {
        float4 s = imgP4[g];
        #pragma unroll
        for (int zz = 1; zz < ISPL; ++zz) {
            const float4 p = imgP4[zz * (NIMG / 4) + g];
            s.x += p.x; s.y += p.y; s.z += p.z; s.w += p.w;
        }
        const float4 bb = b14[g & (HID / 4 - 1)];
        s.x += bb.x; s.y += bb.y; s.z += bb.z; s.w += bb.w;
        ((float4*)imgF)[g] = s;
    } else if (g < NIMG / 4 + NATTR / 4) {
        const int j = g - NIMG / 4;
        float4 s = attrP4[j];
        #pragma unroll
        for (int zz = 1; zz < ASPL; ++zz) {
            const float4 p = attrP4[zz * (NATTR / 4) + j];
            s.x += p.x; s.y += p.y; s.z += p.z; s.w += p.w;
        }
        ((float4*)attrF)[j] = s;
    }
}

// ---------------------------------------------------------------------------
// Pair kernel: out[b,c] = sigmoid( sum_h relu(imgF[b,h]+attrF[c,h]) * W2[h] + b2 )
// 16x16 (b,c) tile per block; full H=512 staged in LDS once (68 KB),
// single barrier, then pure LDS+VALU inner loop.
// ---------------------------------------------------------------------------
__global__ __launch_bounds__(256) void pair_kernel(
    const float* __restrict__ imgF, const float* __restrict__ attrF,
    const float* __restrict__ W2, const float* __restrict__ b2,
    float* __restrict__ out)
{
    __shared__ float U[TB][HID + 4];
    __shared__ float V[TC][HID + 4];
    __shared__ float w2s[HID];

    const int t  = threadIdx.x;
    const int c0 = blockIdx.x * TC;
    const int b0 = blockIdx.y * TB;

    w2s[t]       = W2[t];
    w2s[t + 256] = W2[t + 256];

    #pragma unroll
    for (int rep = 0; rep < 8; ++rep) {
        const int e   = rep * 256 + t;        // 0..2047
        const int row = e >> 7;               // 0..15
        const int c4  = (e & 127) * 4;        // 0..508
        *(float4*)&U[row][c4] =
            *(const float4*)&imgF[(b0 + row) * HID + c4];
        const int c = c0 + row;
        float4 v = make_float4(0.f, 0.f, 0.f, 0.f);
        if (c < CLS)
            v = *(const float4*)&attrF[c * HID + c4];
        *(float4*)&V[row][c4] = v;
    }
    __syncthreads();

    const int ci = t & 15;
    const int bi = t >> 4;

    float acc = 0.f;
    #pragma unroll 16
    for (int h4 = 0; h4 < HID / 4; ++h4) {
        const float4 u = *(const float4*)&U[bi][h4 * 4];
        const float4 v = *(const float4*)&V[ci][h4 * 4];
        const float4 w = *(const float4*)&w2s[h4 * 4];
        acc = fmaf(fmaxf(u.x + v.x, 0.f), w.x, acc);
        acc = fmaf(fmaxf(u.y + v.y, 0.f), w.y, acc);
        acc = fmaf(fmaxf(u.z + v.z, 0.f), w.z, acc);
        acc = fmaf(fmaxf(u.w + v.w, 0.f), w.w, acc);
    }

    const int b = b0 + bi;
    const int c = c0 + ci;
    if (c < CLS) {
        const float x = acc + b2[0];
        out[b * CLS + c] = 1.f / (1.f + __expf(-x));
    }
}

// ---------------------------------------------------------------------------
extern "C" void kernel_launch(void* const* d_in, const int* in_sizes, int n_in,
                              void* d_out, int out_size, void* d_ws, size_t ws_size,
                              hipStream_t stream) {
    const float* img  = (const float*)d_in[0];   // (128, 1024)
    const float* attr = (const float*)d_in[1];   // (500, 1024)
    const float* W1   = (const float*)d_in[2];   // (512, 2048)
    const float* b1   = (const float*)d_in[3];   // (512,)
    const float* W2   = (const float*)d_in[4];   // (1, 512)
    const float* b2   = (const float*)d_in[5];   // (1,)
    float* out = (float*)d_out;                  // (128, 500)

    float* ws    = (float*)d_ws;
    float* imgP  = ws;                                   // 8*128*512
    float* attrP = imgP  + (size_t)ISPL * NIMG;          // 6*500*512
    float* imgF  = attrP + (size_t)ASPL * NATTR;         // 128*512
    float* attrF = imgF  + (size_t)NIMG;                 // 500*512

    // Stage 1: balanced split-K GEMM, 512 blocks = 2 blocks/CU exactly.
    gemm_bt_splitk<<<dim3(512), 256, 0, stream>>>(img, attr, W1, imgP, attrP);

    // Stage 2: merge partials (+b1 on img side). 80384 float4s.
    const int n4 = NIMG / 4 + NATTR / 4;                 // 80384
    merge_kernel<<<(n4 + 255) / 256, 256, 0, stream>>>(imgP, attrP, b1, imgF, attrF);

    // Stage 3: pair reduction + sigmoid
    dim3 pgrid((CLS + TC - 1) / TC, BATCH / TB);         // 32 x 8 = 256 blocks
    pair_kernel<<<pgrid, 256, 0, stream>>>(imgF, attrF, W2, b2, out);
}

// Round 6
// 93.746 us; speedup vs baseline: 1.0653x; 1.0044x over previous
//
#include <hip/hip_runtime.h>
#include <math.h>

#define BATCH 128
#define FEAT  1024
#define CLS   500
#define HID   512
#define ISPL  8          // img split-K count   (Ks = 128 = 8 BK-steps)
#define ASPL  6          // attr split-K count  (BK-steps 11/11/11/11/10/10)

constexpr int BM = 64, BN = 64, BK = 16;
constexpr int TB = 16, TC = 16;

constexpr int NIMG  = BATCH * HID;   // 65536
constexpr int NATTR = CLS * HID;     // 256000

// ---------------------------------------------------------------------------
// Balanced split-K GEMM, double-buffered LDS, one barrier per K-step.
//   bid <  128 : img path  — z = bid>>4 (8 splits), 2 m-tiles x 8 n-tiles
//   bid >= 128 : attr path — z = a/64   (6 splits), 8 m-tiles x 8 n-tiles
// C = A * B^T, A (M,K) row-major, B rows of length ldb=2*FEAT.
// 512 blocks = exactly 2 blocks/CU on 256 CUs.
// ---------------------------------------------------------------------------
__global__ __launch_bounds__(256) void gemm_bt_splitk(
    const float* __restrict__ img, const float* __restrict__ attr,
    const float* __restrict__ W1,
    float* __restrict__ imgP, float* __restrict__ attrP)
{
    __shared__ float As[2][BK][BM + 4];
    __shared__ float Bs[2][BK][BN + 4];

    const int t   = threadIdx.x;
    const int bid = blockIdx.x;

    const float* A;
    float* P;
    int M, boff, m0, n0, kt0, nkt;
    if (bid < 128) {                       // image path
        const int z   = bid >> 4;          // 0..7
        const int rem = bid & 15;
        A = img; P = imgP + (size_t)z * NIMG;
        M = BATCH; boff = 0;
        m0 = (rem >> 3) * BM;              // 0..1
        n0 = (rem & 7) * BN;
        kt0 = z * 8;  nkt = 8;             // 8 BK-steps per split
    } else {                               // attribute path
        const int a   = bid - 128;
        const int z   = a / 64;            // 0..5
        const int rem = a & 63;
        A = attr; P = attrP + (size_t)z * NATTR;
        M = CLS; boff = FEAT;
        m0 = (rem >> 3) * BM;              // 0..7
        n0 = (rem & 7) * BN;
        kt0 = (z < 4) ? z * 11 : 44 + (z - 4) * 10;
        nkt = (z < 4) ? 11 : 10;           // 11+11+11+11+10+10 = 64 steps
    }

    const int K   = FEAT;
    const int ldb = 2 * FEAT;

    const int lrow = t >> 2;               // 0..63
    const int lk   = (t & 3) * 4;          // 0,4,8,12
    const int tn   = t & 15;               // n micro index
    const int tm   = t >> 4;               // m micro index

    const int mrow = m0 + lrow;
    const bool mok = (mrow < M);
    const float* Aptr = A  + (size_t)mrow * K + lk;            // + kk
    const float* Bptr = W1 + (size_t)(n0 + lrow) * ldb + boff + lk;

    // prologue: stage K-step 0 into buffer 0
    {
        const int kk = kt0 * BK;
        float4 av = make_float4(0.f, 0.f, 0.f, 0.f);
        if (mok) av = *(const float4*)&Aptr[kk];
        const float4 bv = *(const float4*)&Bptr[kk];
        As[0][lk + 0][lrow] = av.x; As[0][lk + 1][lrow] = av.y;
        As[0][lk + 2][lrow] = av.z; As[0][lk + 3][lrow] = av.w;
        Bs[0][lk + 0][lrow] = bv.x; Bs[0][lk + 1][lrow] = bv.y;
        Bs[0][lk + 2][lrow] = bv.z; Bs[0][lk + 3][lrow] = bv.w;
    }

    float acc[4][4];
    #pragma unroll
    for (int i = 0; i < 4; ++i)
        #pragma unroll
        for (int j = 0; j < 4; ++j) acc[i][j] = 0.f;

    for (int kt = 0; kt < nkt; ++kt) {
        __syncthreads();                   // buf 'cur' ready for everyone
        const int cur  = kt & 1;
        const bool more = (kt + 1 < nkt);

        // issue next tile's global loads BEFORE compute — latency hides
        float4 av = make_float4(0.f, 0.f, 0.f, 0.f), bv;
        if (more) {
            const int kk = (kt0 + kt + 1) * BK;
            if (mok) av = *(const float4*)&Aptr[kk];
            bv = *(const float4*)&Bptr[kk];
        }

        #pragma unroll
        for (int k = 0; k < BK; ++k) {
            const float4 a = *(const float4*)&As[cur][k][tm * 4];
            const float4 b = *(const float4*)&Bs[cur][k][tn * 4];
            acc[0][0] = fmaf(a.x, b.x, acc[0][0]);
            acc[0][1] = fmaf(a.x, b.y, acc[0][1]);
            acc[0][2] = fmaf(a.x, b.z, acc[0][2]);
            acc[0][3] = fmaf(a.x, b.w, acc[0][3]);
            acc[1][0] = fmaf(a.y, b.x, acc[1][0]);
            acc[1][1] = fmaf(a.y, b.y, acc[1][1]);
            acc[1][2] = fmaf(a.y, b.z, acc[1][2]);
            acc[1][3] = fmaf(a.y, b.w, acc[1][3]);
            acc[2][0] = fmaf(a.z, b.x, acc[2][0]);
            acc[2][1] = fmaf(a.z, b.y, acc[2][1]);
            acc[2][2] = fmaf(a.z, b.z, acc[2][2]);
            acc[2][3] = fmaf(a.z, b.w, acc[2][3]);
            acc[3][0] = fmaf(a.w, b.x, acc[3][0]);
            acc[3][1] = fmaf(a.w, b.y, acc[3][1]);
            acc[3][2] = fmaf(a.w, b.z, acc[3][2]);
            acc[3][3] = fmaf(a.w, b.w, acc[3][3]);
        }

        if (more) {                        // write next tile to other buffer
            const int nxt = cur ^ 1;
            As[nxt][lk + 0][lrow] = av.x; As[nxt][lk + 1][lrow] = av.y;
            As[nxt][lk + 2][lrow] = av.z; As[nxt][lk + 3][lrow] = av.w;
            Bs[nxt][lk + 0][lrow] = bv.x; Bs[nxt][lk + 1][lrow] = bv.y;
            Bs[nxt][lk + 2][lrow] = bv.z; Bs[nxt][lk + 3][lrow] = bv.w;
        }
    }

    #pragma unroll
    for (int i = 0; i < 4; ++i) {
        const int m = m0 + tm * 4 + i;
        if (m < M) {
            float4 v = make_float4(acc[i][0], acc[i][1], acc[i][2], acc[i][3]);
            *(float4*)&P[(size_t)m * HID + n0 + tn * 4] = v;
        }
    }
}

// ---------------------------------------------------------------------------
// Merge split-K partials (8 img layers, 6 attr layers); fold b1 into img.
// One float4 per thread.
// ---------------------------------------------------------------------------
__global__ __launch_bounds__(256) void merge_kernel(
    const float* __restrict__ imgP, const float* __restrict__ attrP,
    const float* __restrict__ b1,
    float* __restrict__ imgF, float* __restrict__ attrF)
{
    const int g = blockIdx.x * 256 + threadIdx.x;     // float4 index
    const float4* imgP4  = (const float4*)imgP;
    const float4* attrP4 = (const float4*)attrP;
    const float4* b14    = (const float4*)b1;
    if (g < NIMG / 4) {
        float4 s = imgP4[g];
        #pragma unroll
        for (int zz = 1; zz < ISPL; ++zz) {
            const float4 p = imgP4[zz * (NIMG / 4) + g];
            s.x += p.x; s.y += p.y; s.z += p.z; s.w += p.w;
        }
        const float4 bb = b14[g & (HID / 4 - 1)];
        s.x += bb.x; s.y += bb.y; s.z += bb.z; s.w += bb.w;
        ((float4*)imgF)[g] = s;
    } else if (g < NIMG / 4 + NATTR / 4) {
        const int j = g - NIMG / 4;
        float4 s = attrP4[j];
        #pragma unroll
        for (int zz = 1; zz < ASPL; ++zz) {
            const float4 p = attrP4[zz * (NATTR / 4) + j];
            s.x += p.x; s.y += p.y; s.z += p.z; s.w += p.w;
        }
        ((float4*)attrF)[j] = s;
    }
}

// ---------------------------------------------------------------------------
// Pair kernel: out[b,c] = sigmoid( sum_h relu(imgF[b,h]+attrF[c,h]) * W2[h] + b2 )
// 16x16 (b,c) tile per block; full H=512 staged in LDS once (68 KB),
// single barrier, then pure LDS+VALU inner loop.
// ---------------------------------------------------------------------------
__global__ __launch_bounds__(256) void pair_kernel(
    const float* __restrict__ imgF, const float* __restrict__ attrF,
    const float* __restrict__ W2, const float* __restrict__ b2,
    float* __restrict__ out)
{
    __shared__ float U[TB][HID + 4];
    __shared__ float V[TC][HID + 4];
    __shared__ float w2s[HID];

    const int t  = threadIdx.x;
    const int c0 = blockIdx.x * TC;
    const int b0 = blockIdx.y * TB;

    w2s[t]       = W2[t];
    w2s[t + 256] = W2[t + 256];

    #pragma unroll
    for (int rep = 0; rep < 8; ++rep) {
        const int e   = rep * 256 + t;        // 0..2047
        const int row = e >> 7;               // 0..15
        const int c4  = (e & 127) * 4;        // 0..508
        *(float4*)&U[row][c4] =
            *(const float4*)&imgF[(b0 + row) * HID + c4];
        const int c = c0 + row;
        float4 v = make_float4(0.f, 0.f, 0.f, 0.f);
        if (c < CLS)
            v = *(const float4*)&attrF[c * HID + c4];
        *(float4*)&V[row][c4] = v;
    }
    __syncthreads();

    const int ci = t & 15;
    const int bi = t >> 4;

    float acc = 0.f;
    #pragma unroll 16
    for (int h4 = 0; h4 < HID / 4; ++h4) {
        const float4 u = *(const float4*)&U[bi][h4 * 4];
        const float4 v = *(const float4*)&V[ci][h4 * 4];
        const float4 w = *(const float4*)&w2s[h4 * 4];
        acc = fmaf(fmaxf(u.x + v.x, 0.f), w.x, acc);
        acc = fmaf(fmaxf(u.y + v.y, 0.f), w.y, acc);
        acc = fmaf(fmaxf(u.z + v.z, 0.f), w.z, acc);
        acc = fmaf(fmaxf(u.w + v.w, 0.f), w.w, acc);
    }

    const int b = b0 + bi;
    const int c = c0 + ci;
    if (c < CLS) {
        const float x = acc + b2[0];
        out[b * CLS + c] = 1.f / (1.f + __expf(-x));
    }
}

// ---------------------------------------------------------------------------
extern "C" void kernel_launch(void* const* d_in, const int* in_sizes, int n_in,
                              void* d_out, int out_size, void* d_ws, size_t ws_size,
                              hipStream_t stream) {
    const float* img  = (const float*)d_in[0];   // (128, 1024)
    const float* attr = (const float*)d_in[1];   // (500, 1024)
    const float* W1   = (const float*)d_in[2];   // (512, 2048)
    const float* b1   = (const float*)d_in[3];   // (512,)
    const float* W2   = (const float*)d_in[4];   // (1, 512)
    const float* b2   = (const float*)d_in[5];   // (1,)
    float* out = (float*)d_out;                  // (128, 500)

    float* ws    = (float*)d_ws;
    float* imgP  = ws;                                   // 8*128*512
    float* attrP = imgP  + (size_t)ISPL * NIMG;          // 6*500*512
    float* imgF  = attrP + (size_t)ASPL * NATTR;         // 128*512
    float* attrF = imgF  + (size_t)NIMG;                 // 500*512

    // Stage 1: balanced split-K GEMM, 512 blocks = 2 blocks/CU exactly.
    gemm_bt_splitk<<<dim3(512), 256, 0, stream>>>(img, attr, W1, imgP, attrP);

    // Stage 2: merge partials (+b1 on img side). 80384 float4s.
    const int n4 = NIMG / 4 + NATTR / 4;                 // 80384
    merge_kernel<<<(n4 + 255) / 256, 256, 0, stream>>>(imgP, attrP, b1, imgF, attrF);

    // Stage 3: pair reduction + sigmoid
    dim3 pgrid((CLS + TC - 1) / TC, BATCH / TB);         // 32 x 8 = 256 blocks
    pair_kernel<<<pgrid, 256, 0, stream>>>(imgF, attrF, W2, b2, out);
}

// Round 7
// 92.183 us; speedup vs baseline: 1.0834x; 1.0170x over previous
//
#include <hip/hip_runtime.h>
#include <math.h>

#define BATCH 128
#define FEAT  1024
#define CLS   500
#define HID   512
#define ISPL  8          // img split-K count   (Ks = 128 = 8 BK-steps)
#define ASPL  6          // attr split-K count  (BK-steps 11/11/11/11/10/10)

constexpr int BM = 64, BN = 64, BK = 16;
constexpr int TB = 16, TC = 16;

constexpr int NIMG  = BATCH * HID;   // 65536
constexpr int NATTR = CLS * HID;     // 256000

// ---------------------------------------------------------------------------
// Balanced split-K GEMM, double-buffered LDS, one barrier per K-step.
// (byte-identical to the twice-verified round-3/round-6 version)
// ---------------------------------------------------------------------------
__global__ __launch_bounds__(256) void gemm_bt_splitk(
    const float* __restrict__ img, const float* __restrict__ attr,
    const float* __restrict__ W1,
    float* __restrict__ imgP, float* __restrict__ attrP)
{
    __shared__ float As[2][BK][BM + 4];
    __shared__ float Bs[2][BK][BN + 4];

    const int t   = threadIdx.x;
    const int bid = blockIdx.x;

    const float* A;
    float* P;
    int M, boff, m0, n0, kt0, nkt;
    if (bid < 128) {                       // image path
        const int z   = bid >> 4;          // 0..7
        const int rem = bid & 15;
        A = img; P = imgP + (size_t)z * NIMG;
        M = BATCH; boff = 0;
        m0 = (rem >> 3) * BM;              // 0..1
        n0 = (rem & 7) * BN;
        kt0 = z * 8;  nkt = 8;             // 8 BK-steps per split
    } else {                               // attribute path
        const int a   = bid - 128;
        const int z   = a / 64;            // 0..5
        const int rem = a & 63;
        A = attr; P = attrP + (size_t)z * NATTR;
        M = CLS; boff = FEAT;
        m0 = (rem >> 3) * BM;              // 0..7
        n0 = (rem & 7) * BN;
        kt0 = (z < 4) ? z * 11 : 44 + (z - 4) * 10;
        nkt = (z < 4) ? 11 : 10;           // 11+11+11+11+10+10 = 64 steps
    }

    const int K   = FEAT;
    const int ldb = 2 * FEAT;

    const int lrow = t >> 2;               // 0..63
    const int lk   = (t & 3) * 4;          // 0,4,8,12
    const int tn   = t & 15;               // n micro index
    const int tm   = t >> 4;               // m micro index

    const int mrow = m0 + lrow;
    const bool mok = (mrow < M);
    const float* Aptr = A  + (size_t)mrow * K + lk;            // + kk
    const float* Bptr = W1 + (size_t)(n0 + lrow) * ldb + boff + lk;

    // prologue: stage K-step 0 into buffer 0
    {
        const int kk = kt0 * BK;
        float4 av = make_float4(0.f, 0.f, 0.f, 0.f);
        if (mok) av = *(const float4*)&Aptr[kk];
        const float4 bv = *(const float4*)&Bptr[kk];
        As[0][lk + 0][lrow] = av.x; As[0][lk + 1][lrow] = av.y;
        As[0][lk + 2][lrow] = av.z; As[0][lk + 3][lrow] = av.w;
        Bs[0][lk + 0][lrow] = bv.x; Bs[0][lk + 1][lrow] = bv.y;
        Bs[0][lk + 2][lrow] = bv.z; Bs[0][lk + 3][lrow] = bv.w;
    }

    float acc[4][4];
    #pragma unroll
    for (int i = 0; i < 4; ++i)
        #pragma unroll
        for (int j = 0; j < 4; ++j) acc[i][j] = 0.f;

    for (int kt = 0; kt < nkt; ++kt) {
        __syncthreads();                   // buf 'cur' ready for everyone
        const int cur  = kt & 1;
        const bool more = (kt + 1 < nkt);

        // issue next tile's global loads BEFORE compute — latency hides
        float4 av = make_float4(0.f, 0.f, 0.f, 0.f), bv;
        if (more) {
            const int kk = (kt0 + kt + 1) * BK;
            if (mok) av = *(const float4*)&Aptr[kk];
            bv = *(const float4*)&Bptr[kk];
        }

        #pragma unroll
        for (int k = 0; k < BK; ++k) {
            const float4 a = *(const float4*)&As[cur][k][tm * 4];
            const float4 b = *(const float4*)&Bs[cur][k][tn * 4];
            acc[0][0] = fmaf(a.x, b.x, acc[0][0]);
            acc[0][1] = fmaf(a.x, b.y, acc[0][1]);
            acc[0][2] = fmaf(a.x, b.z, acc[0][2]);
            acc[0][3] = fmaf(a.x, b.w, acc[0][3]);
            acc[1][0] = fmaf(a.y, b.x, acc[1][0]);
            acc[1][1] = fmaf(a.y, b.y, acc[1][1]);
            acc[1][2] = fmaf(a.y, b.z, acc[1][2]);
            acc[1][3] = fmaf(a.y, b.w, acc[1][3]);
            acc[2][0] = fmaf(a.z, b.x, acc[2][0]);
            acc[2][1] = fmaf(a.z, b.y, acc[2][1]);
            acc[2][2] = fmaf(a.z, b.z, acc[2][2]);
            acc[2][3] = fmaf(a.z, b.w, acc[2][3]);
            acc[3][0] = fmaf(a.w, b.x, acc[3][0]);
            acc[3][1] = fmaf(a.w, b.y, acc[3][1]);
            acc[3][2] = fmaf(a.w, b.z, acc[3][2]);
            acc[3][3] = fmaf(a.w, b.w, acc[3][3]);
        }

        if (more) {                        // write next tile to other buffer
            const int nxt = cur ^ 1;
            As[nxt][lk + 0][lrow] = av.x; As[nxt][lk + 1][lrow] = av.y;
            As[nxt][lk + 2][lrow] = av.z; As[nxt][lk + 3][lrow] = av.w;
            Bs[nxt][lk + 0][lrow] = bv.x; Bs[nxt][lk + 1][lrow] = bv.y;
            Bs[nxt][lk + 2][lrow] = bv.z; Bs[nxt][lk + 3][lrow] = bv.w;
        }
    }

    #pragma unroll
    for (int i = 0; i < 4; ++i) {
        const int m = m0 + tm * 4 + i;
        if (m < M) {
            float4 v = make_float4(acc[i][0], acc[i][1], acc[i][2], acc[i][3]);
            *(float4*)&P[(size_t)m * HID + n0 + tn * 4] = v;
        }
    }
}

// ---------------------------------------------------------------------------
// Merge split-K partials (8 img layers, 6 attr layers); fold b1 into img.
// One float4 per thread. (unchanged, verified)
// ---------------------------------------------------------------------------
__global__ __launch_bounds__(256) void merge_kernel(
    const float* __restrict__ imgP, const float* __restrict__ attrP,
    const float* __restrict__ b1,
    float* __restrict__ imgF, float* __restrict__ attrF)
{
    const int g = blockIdx.x * 256 + threadIdx.x;     // float4 index
    const float4* imgP4  = (const float4*)imgP;
    const float4* attrP4 = (const float4*)attrP;
    const float4* b14    = (const float4*)b1;
    if (g < NIMG / 4) {
        float4 s = imgP4[g];
        #pragma unroll
        for (int zz = 1; zz < ISPL; ++zz) {
            const float4 p = imgP4[zz * (NIMG / 4) + g];
            s.x += p.x; s.y += p.y; s.z += p.z; s.w += p.w;
        }
        const float4 bb = b14[g & (HID / 4 - 1)];
        s.x += bb.x; s.y += bb.y; s.z += bb.z; s.w += bb.w;
        ((float4*)imgF)[g] = s;
    } else if (g < NIMG / 4 + NATTR / 4) {
        const int j = g - NIMG / 4;
        float4 s = attrP4[j];
        #pragma unroll
        for (int zz = 1; zz < ASPL; ++zz) {
            const float4 p = attrP4[zz * (NATTR / 4) + j];
            s.x += p.x; s.y += p.y; s.z += p.z; s.w += p.w;
        }
        ((float4*)attrF)[j] = s;
    }
}

// ---------------------------------------------------------------------------
// Pair kernel v2: out[b,c] = sigmoid( sum_h relu(imgF[b,h]+attrF[c,h])*W2[h]+b2 )
// 16x16 (b,c) tile per block. Register blocking: each thread owns 4 c's and
// one h-quarter (wave id == h-quarter), so per 4h we issue 6 ds_read_b128
// for 4 outputs (was 3 reads for 1 output) — flips LDS-bound to VALU-bound.
// u is a 4-lane broadcast, each v a 16-lane broadcast, w a full broadcast.
// 4 KB LDS reduction combines the four h-quarter partials.
// ---------------------------------------------------------------------------
__global__ __launch_bounds__(256) void pair_kernel(
    const float* __restrict__ imgF, const float* __restrict__ attrF,
    const float* __restrict__ W2, const float* __restrict__ b2,
    float* __restrict__ out)
{
    __shared__ float U[TB][HID + 4];
    __shared__ float V[TC][HID + 4];
    __shared__ float w2s[HID];
    __shared__ float red[4][TB][TC];      // [h-quarter][bi][c]

    const int t  = threadIdx.x;
    const int c0 = blockIdx.x * TC;
    const int b0 = blockIdx.y * TB;

    w2s[t]       = W2[t];
    w2s[t + 256] = W2[t + 256];

    #pragma unroll
    for (int rep = 0; rep < 8; ++rep) {
        const int e   = rep * 256 + t;        // 0..2047
        const int row = e >> 7;               // 0..15
        const int c4  = (e & 127) * 4;        // 0..508
        *(float4*)&U[row][c4] =
            *(const float4*)&imgF[(b0 + row) * HID + c4];
        const int c = c0 + row;
        float4 v = make_float4(0.f, 0.f, 0.f, 0.f);
        if (c < CLS)
            v = *(const float4*)&attrF[c * HID + c4];
        *(float4*)&V[row][c4] = v;
    }
    __syncthreads();

    const int q  = t >> 6;                    // h-quarter 0..3 (== wave id)
    const int bi = (t >> 2) & 15;             // b row within tile
    const int cg = t & 3;                     // c group: owns c = cg*4..cg*4+3

    float4 acc4 = make_float4(0.f, 0.f, 0.f, 0.f);  // per owned c

    #pragma unroll 8
    for (int i = 0; i < HID / 4 / 4; ++i) {   // 32 iters over own h-quarter
        const int h = (q * 32 + i) * 4;
        const float4 u  = *(const float4*)&U[bi][h];
        const float4 w  = *(const float4*)&w2s[h];
        const float4 v0 = *(const float4*)&V[cg * 4 + 0][h];
        const float4 v1 = *(const float4*)&V[cg * 4 + 1][h];
        const float4 v2 = *(const float4*)&V[cg * 4 + 2][h];
        const float4 v3 = *(const float4*)&V[cg * 4 + 3][h];

        acc4.x = fmaf(fmaxf(u.x + v0.x, 0.f), w.x, acc4.x);
        acc4.x = fmaf(fmaxf(u.y + v0.y, 0.f), w.y, acc4.x);
        acc4.x = fmaf(fmaxf(u.z + v0.z, 0.f), w.z, acc4.x);
        acc4.x = fmaf(fmaxf(u.w + v0.w, 0.f), w.w, acc4.x);

        acc4.y = fmaf(fmaxf(u.x + v1.x, 0.f), w.x, acc4.y);
        acc4.y = fmaf(fmaxf(u.y + v1.y, 0.f), w.y, acc4.y);
        acc4.y = fmaf(fmaxf(u.z + v1.z, 0.f), w.z, acc4.y);
        acc4.y = fmaf(fmaxf(u.w + v1.w, 0.f), w.w, acc4.y);

        acc4.z = fmaf(fmaxf(u.x + v2.x, 0.f), w.x, acc4.z);
        acc4.z = fmaf(fmaxf(u.y + v2.y, 0.f), w.y, acc4.z);
        acc4.z = fmaf(fmaxf(u.z + v2.z, 0.f), w.z, acc4.z);
        acc4.z = fmaf(fmaxf(u.w + v2.w, 0.f), w.w, acc4.z);

        acc4.w = fmaf(fmaxf(u.x + v3.x, 0.f), w.x, acc4.w);
        acc4.w = fmaf(fmaxf(u.y + v3.y, 0.f), w.y, acc4.w);
        acc4.w = fmaf(fmaxf(u.z + v3.z, 0.f), w.z, acc4.w);
        acc4.w = fmaf(fmaxf(u.w + v3.w, 0.f), w.w, acc4.w);
    }

    if (q != 0) *(float4*)&red[q][bi][cg * 4] = acc4;
    __syncthreads();

    if (q == 0) {
        #pragma unroll
        for (int qq = 1; qq < 4; ++qq) {
            const float4 r = *(const float4*)&red[qq][bi][cg * 4];
            acc4.x += r.x; acc4.y += r.y; acc4.z += r.z; acc4.w += r.w;
        }
        const int b  = b0 + bi;
        const int c  = c0 + cg * 4;
        const float bb = b2[0];
        const float vals[4] = {acc4.x, acc4.y, acc4.z, acc4.w};
        #pragma unroll
        for (int j = 0; j < 4; ++j) {
            if (c + j < CLS)
                out[b * CLS + c + j] =
                    1.f / (1.f + __expf(-(vals[j] + bb)));
        }
    }
}

// ---------------------------------------------------------------------------
extern "C" void kernel_launch(void* const* d_in, const int* in_sizes, int n_in,
                              void* d_out, int out_size, void* d_ws, size_t ws_size,
                              hipStream_t stream) {
    const float* img  = (const float*)d_in[0];   // (128, 1024)
    const float* attr = (const float*)d_in[1];   // (500, 1024)
    const float* W1   = (const float*)d_in[2];   // (512, 2048)
    const float* b1   = (const float*)d_in[3];   // (512,)
    const float* W2   = (const float*)d_in[4];   // (1, 512)
    const float* b2   = (const float*)d_in[5];   // (1,)
    float* out = (float*)d_out;                  // (128, 500)

    float* ws    = (float*)d_ws;
    float* imgP  = ws;                                   // 8*128*512
    float* attrP = imgP  + (size_t)ISPL * NIMG;          // 6*500*512
    float* imgF  = attrP + (size_t)ASPL * NATTR;         // 128*512
    float* attrF = imgF  + (size_t)NIMG;                 // 500*512

    // Stage 1: balanced split-K GEMM, 512 blocks = 2 blocks/CU exactly.
    gemm_bt_splitk<<<dim3(512), 256, 0, stream>>>(img, attr, W1, imgP, attrP);

    // Stage 2: merge partials (+b1 on img side). 80384 float4s.
    const int n4 = NIMG / 4 + NATTR / 4;                 // 80384
    merge_kernel<<<(n4 + 255) / 256, 256, 0, stream>>>(imgP, attrP, b1, imgF, attrF);

    // Stage 3: pair reduction + sigmoid (register-blocked v2)
    dim3 pgrid((CLS + TC - 1) / TC, BATCH / TB);         // 32 x 8 = 256 blocks
    pair_kernel<<<pgrid, 256, 0, stream>>>(imgF, attrF, W2, b2, out);
}